// Round 5
// baseline (367.205 us; speedup 1.0000x reference)
//
#include <hip/hip_runtime.h>
#include <hip/hip_cooperative_groups.h>
#include <math.h>

namespace cg = cooperative_groups;

#define BATCH 8
#define CH    256
#define H     128
#define W     128
#define HW    (H * W)            // 16384
#define OH    65
#define OW    65
#define NPIX  (OH * OW)          // 4225
#define CSPLIT 4                 // channel splits per pool unit
#define CPW   (CH / CSPLIT / 4)  // 16 channels per wave
#define NORMBLK 512              // blocks active in phase 1
#define POOLUNITS (OH * BATCH * CSPLIT)  // 2080
#define GRID  1024               // co-resident: 4 blocks/CU at launch_bounds(256,4)

// One cooperative kernel. Phase 1: per-pixel channel L2 norm (x read once, HBM;
// x becomes L3-resident: 128 MiB < 256 MiB L3). grid.sync(). Phase 2: softmax-
// weighted 3x3/s2 pooling, row-cooperative shuffle structure (verified R4 body),
// x served from L3.
__global__ __launch_bounds__(256, 4) void fused_kernel(const float* __restrict__ x,
                                                       float* __restrict__ nbuf,
                                                       float* __restrict__ out) {
    __shared__ float4 part[4][64];
    __shared__ float wts[OW][9];
    const int t    = threadIdx.x;
    const int lane = t & 63;
    const int wv   = t >> 6;

    // ---------- Phase 1: norms ----------
    if (blockIdx.x < NORMBLK) {
        const float4* x4 = (const float4*)x;
        const int q   = blockIdx.x * 64 + lane;   // pixel-quad index
        const int b   = (q * 4) >> 14;            // / HW
        const int qin = q - b * (HW / 4);
        const float4* p = x4 + (size_t)(b * CH + wv * 64) * (HW / 4) + qin;
        float4 acc = {0.f, 0.f, 0.f, 0.f};
        #pragma unroll 8
        for (int c = 0; c < 64; ++c) {
            float4 v = p[(size_t)c * (HW / 4)];
            acc.x += v.x * v.x; acc.y += v.y * v.y;
            acc.z += v.z * v.z; acc.w += v.w * v.w;
        }
        part[wv][lane] = acc;
        __syncthreads();
        if (wv == 0) {
            float4 a0 = part[0][lane], a1 = part[1][lane];
            float4 a2 = part[2][lane], a3 = part[3][lane];
            float4 r;
            r.x = sqrtf(a0.x + a1.x + a2.x + a3.x);
            r.y = sqrtf(a0.y + a1.y + a2.y + a3.y);
            r.z = sqrtf(a0.z + a1.z + a2.z + a3.z);
            r.w = sqrtf(a0.w + a1.w + a2.w + a3.w);
            ((float4*)nbuf)[q] = r;
        }
    }

    cg::this_grid().sync();   // device-scope fence: norms visible grid-wide

    // ---------- Phase 2: pooling, grid-stride over 2080 units ----------
    for (int vb = blockIdx.x; vb < POOLUNITS; vb += GRID) {
        const int z   = vb / (OH * BATCH);
        const int rem = vb - z * (OH * BATCH);
        const int b   = rem / OH;
        const int oh  = rem - b * OH;

        // Phase A: softmax weights for the 65 output pixels of this row.
        if (t < OW) {
            const float* nb = nbuf + b * HW;
            const int iw0 = 2 * t - 2;
            float ww[9];
            bool  vl[9];
            float m = 0.f;   // OOB norms are 0 -> max starts at 0
            #pragma unroll
            for (int r = 0; r < 3; ++r) {
                int ih = 2 * oh + r - 2;
                bool vh = (unsigned)ih < (unsigned)H;
                int ihc = ih < 0 ? 0 : (ih > H - 1 ? H - 1 : ih);
                #pragma unroll
                for (int kw = 0; kw < 3; ++kw) {
                    int iw = iw0 + kw;
                    bool v = vh && ((unsigned)iw < (unsigned)W);
                    int iwc = iw < 0 ? 0 : (iw > W - 1 ? W - 1 : iw);
                    float nv = v ? nb[ihc * W + iwc] : 0.f;
                    vl[r * 3 + kw] = v;
                    ww[r * 3 + kw] = nv;
                    m = fmaxf(m, nv);
                }
            }
            float d = 0.f;
            #pragma unroll
            for (int k = 0; k < 9; ++k) {
                float e = __expf(ww[k] - m);   // OOB contributes exp(0-m) to denom
                d += e;
                ww[k] = vl[k] ? e : 0.f;       // but zero weight in numerator
            }
            float inv = 1.f / d;
            #pragma unroll
            for (int k = 0; k < 9; ++k) wts[t][k] = ww[k] * inv;
        }
        __syncthreads();

        float w0[9], w64[9];
        #pragma unroll
        for (int k = 0; k < 9; ++k) { w0[k] = wts[lane][k]; w64[k] = wts[OW - 1][k]; }

        int rb[3];
        #pragma unroll
        for (int r = 0; r < 3; ++r) {
            int ih = 2 * oh + r - 2;
            int ihc = ih < 0 ? 0 : (ih > H - 1 ? H - 1 : ih);
            rb[r] = ihc * W;
        }

        const int cbase = z * (CH / CSPLIT) + wv * CPW;
        const float* xb = x + (size_t)(b * CH + cbase) * HW;
        float*       ob = out + (size_t)(b * CH + cbase) * NPIX + oh * OW;

        #pragma unroll 4
        for (int c = 0; c < CPW; ++c) {
            const float* xc = xb + (size_t)c * HW;
            float2 own[3], prev[3];
            #pragma unroll
            for (int r = 0; r < 3; ++r)
                own[r] = *(const float2*)(xc + rb[r] + 2 * lane);   // cols 2l, 2l+1
            #pragma unroll
            for (int r = 0; r < 3; ++r) {
                prev[r].x = __shfl_up(own[r].x, 1);                 // col 2l-2
                prev[r].y = __shfl_up(own[r].y, 1);                 // col 2l-1
            }
            float a0 = 0.f, a1 = 0.f;
            #pragma unroll
            for (int r = 0; r < 3; ++r) {
                a0 += w0[r * 3 + 0] * prev[r].x + w0[r * 3 + 1] * prev[r].y
                    + w0[r * 3 + 2] * own[r].x;
                a1 += w64[r * 3 + 0] * own[r].x + w64[r * 3 + 1] * own[r].y;
                // pixel 64's third tap (col 128) is OOB -> weight 0
            }
            float* oc = ob + (size_t)c * NPIX;
            oc[lane] = a0;                       // coalesced 256 B
            if (lane == 63) oc[OW - 1] = a1;     // pixel 64 (taps = lane 63's own)
        }
        __syncthreads();   // wts reused next vb iteration
    }
}

extern "C" void kernel_launch(void* const* d_in, const int* in_sizes, int n_in,
                              void* d_out, int out_size, void* d_ws, size_t ws_size,
                              hipStream_t stream) {
    const float* x = (const float*)d_in[0];
    float* out  = (float*)d_out;
    float* nbuf = (float*)d_ws;   // BATCH*H*W floats = 512 KB of scratch

    void* args[] = {(void*)&x, (void*)&nbuf, (void*)&out};
    hipLaunchCooperativeKernel((const void*)fused_kernel, dim3(GRID), dim3(256),
                               args, 0, stream);
}

// Round 6
// 232.643 us; speedup vs baseline: 1.5784x; 1.5784x over previous
//
#include <hip/hip_runtime.h>
#include <math.h>

#define BATCH 8
#define CH    256
#define H     128
#define W     128
#define HW    (H * W)          // 16384
#define OH    65
#define OW    65
#define NPIX  (OH * OW)        // 4225

// One block per output row (b, oh), 512 threads = 8 waves.
// Phase 1: channel-L2 norms for the block's 3 input rows (384 pixels) -> LDS.
//   ~1.5x recompute across adjacent oh blocks; x rows fetched here are re-read
//   L2-hot in phase 2. No inter-block dependency -> no grid sync, one dispatch.
// Phase A: softmax weights for the row's 65 output pixels (once, in LDS).
// Phase 2: each wave pools 32 channels; lane = output pixel; 3 coalesced
//   float2 row-loads per channel; left taps via shfl_up; OOB taps carry
//   exactly-zero weights (reference's zero-padded-norm softmax semantics,
//   verified since R1: absmax 0.0078).
__global__ __launch_bounds__(512, 4) void fused_kernel(const float* __restrict__ x,
                                                       float* __restrict__ out) {
    __shared__ float nrm[3][W];     // 1.5 KB: norms of the 3 input rows (0 if OOB row)
    __shared__ float wts[OW][9];    // 2.3 KB: softmax weights per output pixel
    const int oh   = blockIdx.x;
    const int b    = blockIdx.y;
    const int t    = threadIdx.x;
    const int lane = t & 63;
    const int wv   = t >> 6;

    // ---------- Phase 1: norms for input rows 2*oh-2 .. 2*oh ----------
    if (t < 3 * W) {
        const int r   = t >> 7;         // row slot 0..2
        const int col = t & (W - 1);
        const int ih  = 2 * oh + r - 2;
        float s = 0.f;
        if ((unsigned)ih < (unsigned)H) {
            const float* p = x + (size_t)b * CH * HW + ih * W + col;
            float acc = 0.f;
            #pragma unroll 8
            for (int c = 0; c < CH; ++c) {
                float v = p[(size_t)c * HW];   // coalesced: 64 lanes = 256 B
                acc += v * v;
            }
            s = sqrtf(acc);
        }
        nrm[r][col] = s;                // OOB rows -> 0 (matches zero padding)
    }
    __syncthreads();

    // ---------- Phase A: softmax weights for the 65 output pixels ----------
    if (t < OW) {
        const int iw0 = 2 * t - 2;
        float ww[9];
        bool  vl[9];
        float m = 0.f;                  // OOB norms are 0 -> max starts at 0
        #pragma unroll
        for (int r = 0; r < 3; ++r) {
            int ih = 2 * oh + r - 2;
            bool vh = (unsigned)ih < (unsigned)H;
            #pragma unroll
            for (int kw = 0; kw < 3; ++kw) {
                int iw = iw0 + kw;
                bool v = vh && ((unsigned)iw < (unsigned)W);
                int iwc = iw < 0 ? 0 : (iw > W - 1 ? W - 1 : iw);
                float nv = v ? nrm[r][iwc] : 0.f;
                vl[r * 3 + kw] = v;
                ww[r * 3 + kw] = nv;
                m = fmaxf(m, nv);
            }
        }
        float d = 0.f;
        #pragma unroll
        for (int k = 0; k < 9; ++k) {
            float e = __expf(ww[k] - m);   // OOB contributes exp(0-m) to denom
            d += e;
            ww[k] = vl[k] ? e : 0.f;       // but zero weight in numerator
        }
        float inv = 1.f / d;
        #pragma unroll
        for (int k = 0; k < 9; ++k) wts[t][k] = ww[k] * inv;
    }
    __syncthreads();

    // ---------- Phase 2: pooling; wave wv -> channels [32*wv, 32*wv+32) ----------
    float w0[9], w64[9];
    #pragma unroll
    for (int k = 0; k < 9; ++k) { w0[k] = wts[lane][k]; w64[k] = wts[OW - 1][k]; }

    int rb[3];
    #pragma unroll
    for (int r = 0; r < 3; ++r) {
        int ih = 2 * oh + r - 2;
        int ihc = ih < 0 ? 0 : (ih > H - 1 ? H - 1 : ih);
        rb[r] = ihc * W;                // clamped; invalid rows have zero weights
    }

    const float* xb = x + (size_t)(b * CH + wv * 32) * HW;
    float*       ob = out + (size_t)(b * CH + wv * 32) * NPIX + oh * OW;

    #pragma unroll 4
    for (int c = 0; c < 32; ++c) {
        const float* xc = xb + (size_t)c * HW;
        float2 own[3], prev[3];
        #pragma unroll
        for (int r = 0; r < 3; ++r)
            own[r] = *(const float2*)(xc + rb[r] + 2 * lane);   // cols 2l, 2l+1
        #pragma unroll
        for (int r = 0; r < 3; ++r) {
            prev[r].x = __shfl_up(own[r].x, 1);                 // col 2l-2
            prev[r].y = __shfl_up(own[r].y, 1);                 // col 2l-1
        }
        float a0 = 0.f, a1 = 0.f;
        #pragma unroll
        for (int r = 0; r < 3; ++r) {
            a0 += w0[r * 3 + 0] * prev[r].x + w0[r * 3 + 1] * prev[r].y
                + w0[r * 3 + 2] * own[r].x;
            a1 += w64[r * 3 + 0] * own[r].x + w64[r * 3 + 1] * own[r].y;
            // pixel 64's third tap (col 128) is OOB -> weight 0
        }
        float* oc = ob + (size_t)c * NPIX;
        oc[lane] = a0;                       // coalesced 256 B store
        if (lane == 63) oc[OW - 1] = a1;     // pixel 64 (taps = lane 63's own)
    }
}

extern "C" void kernel_launch(void* const* d_in, const int* in_sizes, int n_in,
                              void* d_out, int out_size, void* d_ws, size_t ws_size,
                              hipStream_t stream) {
    const float* x = (const float*)d_in[0];
    float* out = (float*)d_out;
    dim3 grid(OH, BATCH);   // 520 blocks x 512 threads
    fused_kernel<<<grid, 512, 0, stream>>>(x, out);
}